// Round 6
// baseline (223.661 us; speedup 1.0000x reference)
//
#include <hip/hip_runtime.h>

// B=32, N=1024, D=256. out = softmax((x Wq^T + bq)(x Wk^T + bk)^T) (x Wv^T + bv)
// fp16 MFMA, fp32 accumulate. R6: single-wave (64-thr) blocks, 32 M-rows/wave
// (2 A-sets -> every LDS B-fragment read feeds 2 MFMAs), packed fragment-major
// global layouts + global_load_lds staging. 1024 blocks -> 4 blocks/CU, one
// wave/SIMD; batch-major grid.x clusters each batch's K/V on one XCD's L2.
#define NN 1024
#define DD 256

typedef __attribute__((ext_vector_type(8))) _Float16 f16x8;  // 8 fp16 = 4 VGPRs
typedef __attribute__((ext_vector_type(4))) float f32x4;

union H8 { f16x8 v; _Float16 s[8]; };

__device__ __forceinline__ void g2lds16(const void* g, void* l) {
  __builtin_amdgcn_global_load_lds(
      (const __attribute__((address_space(1))) void*)g,
      (__attribute__((address_space(3))) void*)l, 16, 0, 0);
}

// ---------------- kernel 1: pack W fp32 -> fp16 fragment-major -----------------------
// pw chunk c = ((et*8+kk)*4+nt)*64+lane ; data = W[e=et*64+nt*16+col16][d=kk*32+quad*8..+7]
__global__ void wconv_kernel(const float* __restrict__ Wq, const float* __restrict__ Wk,
                             const float* __restrict__ Wv, _Float16* __restrict__ pw) {
  int c = blockIdx.x * 256 + threadIdx.x;        // < 24576
  int lane = c & 63;
  int nt = (c >> 6) & 3;
  int kk = (c >> 8) & 7;
  int et = c >> 11;                              // 0..11
  int e = et * 64 + nt * 16 + (lane & 15);
  int d = kk * 32 + (lane >> 4) * 8;
  const float* W = (e < 256) ? Wq : (e < 512 ? Wk : Wv);
  const float* src = W + (e & 255) * 256 + d;
  H8 xx;
  for (int j = 0; j < 8; ++j) xx.s[j] = (_Float16)src[j];
  *(f16x8*)(pw + (size_t)c * 8) = xx.v;
}

// ---------------- kernel 2: QKV projection -------------------------------------------
// 1024 blocks x 64 thr. Block = 1 wave, 32 m-rows (2 A-sets) x all 768 e-cols.
// W tile (32KB) staged via global_load_lds; each B-frag read feeds 2 MFMAs.
__global__ __launch_bounds__(64, 1) void proj_kernel(
    const float* __restrict__ traj,
    const float* __restrict__ bq, const float* __restrict__ bk, const float* __restrict__ bv,
    const _Float16* __restrict__ pw,
    _Float16* __restrict__ pq, _Float16* __restrict__ pk, _Float16* __restrict__ pv)
{
  __shared__ _Float16 Wl[16384];      // 32 KB: one 64-col W tile, fragment-major
  __shared__ _Float16 Cs[2560];       // 5120 B epilogue staging -> 37888 B total

  const int t = threadIdx.x;          // == lane, single wave
  const int col16 = t & 15, quad = t >> 4;
  const int mbase = blockIdx.x * 32;
  const int bb = mbase >> 10;

  // A fragments (2 row-groups) from global fp32, once per block.
  f16x8 aq[2][8];
  for (int s = 0; s < 2; ++s) {
    const float* ap = traj + (size_t)(mbase + s * 16 + col16) * DD;
    for (int kk = 0; kk < 8; ++kk) {
      float4 u0 = *(const float4*)(ap + kk * 32 + quad * 8);
      float4 u1 = *(const float4*)(ap + kk * 32 + quad * 8 + 4);
      H8 xx;
      xx.s[0] = (_Float16)u0.x; xx.s[1] = (_Float16)u0.y;
      xx.s[2] = (_Float16)u0.z; xx.s[3] = (_Float16)u0.w;
      xx.s[4] = (_Float16)u1.x; xx.s[5] = (_Float16)u1.y;
      xx.s[6] = (_Float16)u1.z; xx.s[7] = (_Float16)u1.w;
      aq[s][kk] = xx.v;
    }
  }

  const f32x4 zero = {0.f, 0.f, 0.f, 0.f};

  for (int et = 0; et < 12; ++et) {
    __syncthreads();                   // prior Wl/Cs reads retired before overwrite
    {                                  // stage 32 KB W tile, linear 16B/lane
      const _Float16* ws = pw + (size_t)et * 16384;
      for (int i = 0; i < 32; ++i)
        g2lds16(ws + (size_t)(i * 64 + t) * 8, Wl + (i * 64 + t) * 8);
    }
    __syncthreads();                   // staged data visible

    f32x4 acc[2][4];
    for (int s = 0; s < 2; ++s)
      for (int nt = 0; nt < 4; ++nt) acc[s][nt] = zero;
    for (int kk = 0; kk < 8; ++kk)
      for (int nt = 0; nt < 4; ++nt) {
        f16x8 bw = *(const f16x8*)&Wl[((kk * 4 + nt) * 64 + t) * 8];
        acc[0][nt] = __builtin_amdgcn_mfma_f32_16x16x32_f16(aq[0][kk], bw, acc[0][nt], 0, 0, 0);
        acc[1][nt] = __builtin_amdgcn_mfma_f32_16x16x32_f16(aq[1][kk], bw, acc[1][nt], 0, 0, 0);
      }

    int ebase = et * 64;
    int sel = ebase >> 8;              // 0=q 1=k 2=v
    const float* bias = (sel == 0) ? bq : (sel == 1 ? bk : bv);
    for (int nt = 0; nt < 4; ++nt) {
      float bvl = bias[(ebase & 255) + nt * 16 + col16];
      for (int s = 0; s < 2; ++s) {
        acc[s][nt][0] += bvl; acc[s][nt][1] += bvl;
        acc[s][nt][2] += bvl; acc[s][nt][3] += bvl;
      }
    }
    // single-wave LDS round trips: in-order DS pipe, no barriers needed
    if (sel < 2) {
      // stage C layout: row = s*16+quad*4+r (stride 72), col = nt*16+col16
      for (int s = 0; s < 2; ++s)
        for (int nt = 0; nt < 4; ++nt)
          for (int r = 0; r < 4; ++r)
            Cs[(s * 16 + quad * 4 + r) * 72 + nt * 16 + col16] = (_Float16)acc[s][nt][r];
      if (sel == 0) {
        // pq[(g*8 + et*2 + kkloc)*64 + lane], A-frag layout per 16-row group g
        for (int i = 0; i < 4; ++i) {
          int s = i >> 1, kkloc = i & 1;
          f16x8 val = *(const f16x8*)&Cs[(s * 16 + col16) * 72 + kkloc * 32 + quad * 8];
          int g = (mbase >> 4) + s;
          *(f16x8*)(pq + (size_t)((g * 8 + et * 2 + kkloc) * 64 + t) * 8) = val;
        }
      } else {
        // pk[((bb*64+kgg)*8+kkg)*64+lane] = K[key=kgg*16+c16][d=kkg*32+qd*8..]
        for (int i = 0; i < 4; ++i) {
          int kg = i >> 1, kk2 = i & 1;
          f16x8 val = *(const f16x8*)&Cs[(kg * 16 + col16) * 72 + kk2 * 32 + quad * 8];
          int kgg = ((mbase & 1023) >> 4) + kg;
          int kkg = ((ebase - 256) >> 5) + kk2;
          *(f16x8*)(pk + (size_t)(((bb * 64 + kgg) * 8 + kkg) * 64 + t) * 8) = val;
        }
      }
    } else {
      // transposed staging: row = e_local (stride 40), col = m_local
      for (int s = 0; s < 2; ++s)
        for (int nt = 0; nt < 4; ++nt)
          for (int r = 0; r < 4; ++r)
            Cs[(nt * 16 + col16) * 40 + s * 16 + quad * 4 + r] = (_Float16)acc[s][nt][r];
      // pv[((bb*32+kt32)*16+dtg)*64+lane] = V[key=quad*8..][d=dtg*16+c16]
      int kt32 = (mbase & 1023) >> 5;
      for (int dtl = 0; dtl < 4; ++dtl) {
        f16x8 val = *(const f16x8*)&Cs[(dtl * 16 + col16) * 40 + quad * 8];
        int dtg = ((ebase - 512) >> 4) + dtl;
        *(f16x8*)(pv + (size_t)(((bb * 32 + kt32) * 16 + dtg) * 64 + t) * 8) = val;
      }
    }
  }
}

// ---------------- kernel 3: flash attention ------------------------------------------
// grid (32 batches, 32 q-tiles): 1 wave/block, 32 Q-rows (2 A-sets). 32-key tiles
// staged via global_load_lds; every K/V fragment read feeds 2 MFMAs. 35.3 KB LDS
// -> 4 blocks/CU; grid.x=batch clusters each batch's K/V on one XCD.
__global__ __launch_bounds__(64, 1) void attn_kernel(
    const _Float16* __restrict__ pq, const _Float16* __restrict__ pk,
    const _Float16* __restrict__ pv, float* __restrict__ out)
{
  __shared__ _Float16 Ks[8192];       // 16 KB: 32 keys x 256 d, fragment-major
  __shared__ _Float16 Vs[8192];       // 16 KB
  __shared__ _Float16 Ps[32 * 40];    // 2560 B

  const int t = threadIdx.x;          // == lane
  const int col16 = t & 15, quad = t >> 4;
  const int b = blockIdx.x, qt = blockIdx.y;   // bid%8 = b%8 -> per-batch XCD
  const int qrow0 = b * NN + qt * 32;

  // Q fragments (2 row-groups) from packed global
  f16x8 aq[2][8];
  for (int s = 0; s < 2; ++s) {
    int g = b * 64 + qt * 2 + s;
    for (int kk = 0; kk < 8; ++kk)
      aq[s][kk] = *(const f16x8*)(pq + (size_t)((g * 8 + kk) * 64 + t) * 8);
  }

  float m_i[2][4], l_i[2][4], alpha[2][4];
  f32x4 O[2][16];
  const f32x4 zero = {0.f, 0.f, 0.f, 0.f};
  for (int s = 0; s < 2; ++s)
    for (int r = 0; r < 4; ++r) { m_i[s][r] = -3.0e38f; l_i[s][r] = 0.f; }
  for (int s = 0; s < 2; ++s)
    for (int dt = 0; dt < 16; ++dt) O[s][dt] = zero;

  const _Float16* kbb = pk + (size_t)b * 64 * 8 * 64 * 8;
  const _Float16* vbb = pv + (size_t)b * 32 * 16 * 64 * 8;

  for (int kt = 0; kt < 32; ++kt) {
    __syncthreads();                   // prior tile's LDS reads retired
    {                                  // stage K+V tile: 32 KB, linear 16B/lane
      const _Float16* kg = kbb + (size_t)kt * 8192;
      const _Float16* vg = vbb + (size_t)kt * 8192;
      for (int i = 0; i < 16; ++i)
        g2lds16(kg + (size_t)(i * 64 + t) * 8, Ks + (i * 64 + t) * 8);
      for (int i = 0; i < 16; ++i)
        g2lds16(vg + (size_t)(i * 64 + t) * 8, Vs + (i * 64 + t) * 8);
    }
    __syncthreads();                   // staged data visible

    // S = Q K^T (32 keys x 32 rows); each B-frag feeds both row-groups
    f32x4 S[2][2];
    S[0][0] = zero; S[0][1] = zero; S[1][0] = zero; S[1][1] = zero;
    for (int kk = 0; kk < 8; ++kk) {
      f16x8 bk0 = *(const f16x8*)&Ks[((0 * 8 + kk) * 64 + t) * 8];
      f16x8 bk1 = *(const f16x8*)&Ks[((1 * 8 + kk) * 64 + t) * 8];
      S[0][0] = __builtin_amdgcn_mfma_f32_16x16x32_f16(aq[0][kk], bk0, S[0][0], 0, 0, 0);
      S[0][1] = __builtin_amdgcn_mfma_f32_16x16x32_f16(aq[0][kk], bk1, S[0][1], 0, 0, 0);
      S[1][0] = __builtin_amdgcn_mfma_f32_16x16x32_f16(aq[1][kk], bk0, S[1][0], 0, 0, 0);
      S[1][1] = __builtin_amdgcn_mfma_f32_16x16x32_f16(aq[1][kk], bk1, S[1][1], 0, 0, 0);
    }

    // online softmax per row-group; rows quad*4+r private to 16-lane quads
    for (int s = 0; s < 2; ++s)
      for (int r = 0; r < 4; ++r) {
        float vmax = fmaxf(S[s][0][r], S[s][1][r]);
        vmax = fmaxf(vmax, __shfl_xor(vmax, 1));
        vmax = fmaxf(vmax, __shfl_xor(vmax, 2));
        vmax = fmaxf(vmax, __shfl_xor(vmax, 4));
        vmax = fmaxf(vmax, __shfl_xor(vmax, 8));
        float nm = fmaxf(m_i[s][r], vmax);
        alpha[s][r] = __expf(m_i[s][r] - nm);
        float p0 = __expf(S[s][0][r] - nm);
        float p1 = __expf(S[s][1][r] - nm);
        S[s][0][r] = p0; S[s][1][r] = p1;
        float rs = p0 + p1;
        rs += __shfl_xor(rs, 1);
        rs += __shfl_xor(rs, 2);
        rs += __shfl_xor(rs, 4);
        rs += __shfl_xor(rs, 8);
        l_i[s][r] = l_i[s][r] * alpha[s][r] + rs;
        m_i[s][r] = nm;
      }
    for (int s = 0; s < 2; ++s)
      for (int dt = 0; dt < 16; ++dt)
        for (int r = 0; r < 4; ++r) O[s][dt][r] *= alpha[s][r];

    // P -> LDS (C layout -> A layout; single wave, no barrier)
    for (int s = 0; s < 2; ++s)
      for (int nt = 0; nt < 2; ++nt)
        for (int r = 0; r < 4; ++r)
          Ps[(s * 16 + quad * 4 + r) * 40 + nt * 16 + col16] = (_Float16)S[s][nt][r];
    f16x8 ap0 = *(const f16x8*)&Ps[(0 * 16 + col16) * 40 + quad * 8];
    f16x8 ap1 = *(const f16x8*)&Ps[(1 * 16 + col16) * 40 + quad * 8];

    // O += P V; each V fragment feeds both row-groups
    for (int dt = 0; dt < 16; ++dt) {
      f16x8 bv_ = *(const f16x8*)&Vs[(dt * 64 + t) * 8];
      O[0][dt] = __builtin_amdgcn_mfma_f32_16x16x32_f16(ap0, bv_, O[0][dt], 0, 0, 0);
      O[1][dt] = __builtin_amdgcn_mfma_f32_16x16x32_f16(ap1, bv_, O[1][dt], 0, 0, 0);
    }
  }

  // epilogue: O /= l, fp32 store (lanes 0..15 contiguous 64B per instr)
  for (int s = 0; s < 2; ++s)
    for (int r = 0; r < 4; ++r) {
      float inv = 1.0f / l_i[s][r];
      float* orow = out + (size_t)(qrow0 + s * 16 + quad * 4 + r) * DD;
      for (int dt = 0; dt < 16; ++dt)
        orow[dt * 16 + col16] = O[s][dt][r] * inv;
    }
}

// ---------------- launch -------------------------------------------------------------
extern "C" void kernel_launch(void* const* d_in, const int* in_sizes, int n_in,
                              void* d_out, int out_size, void* d_ws, size_t ws_size,
                              hipStream_t stream) {
  const float* traj = (const float*)d_in[0];
  const float* Wq   = (const float*)d_in[1];
  const float* bq   = (const float*)d_in[2];
  const float* Wk   = (const float*)d_in[3];
  const float* bk   = (const float*)d_in[4];
  const float* Wv   = (const float*)d_in[5];
  const float* bv   = (const float*)d_in[6];

  // workspace (fp16): pq 16MB | pk 16MB | pv 16MB | pw 0.4MB  (all packed fragment-major)
  _Float16* pq = (_Float16*)d_ws;
  _Float16* pk = pq + (size_t)32768 * 256;
  _Float16* pv = pk + (size_t)32768 * 256;
  _Float16* pw = pv + (size_t)32768 * 256;   // ~48.4 MB total

  wconv_kernel<<<96, 256, 0, stream>>>(Wq, Wk, Wv, pw);
  proj_kernel<<<1024, 64, 0, stream>>>(traj, bq, bk, bv, pw, pq, pk, pv);
  attn_kernel<<<dim3(32, 32), 64, 0, stream>>>(pq, pk, pv, (float*)d_out);
}

// Round 7
// 182.290 us; speedup vs baseline: 1.2269x; 1.2269x over previous
//
#include <hip/hip_runtime.h>

// B=32, N=1024, D=256. out = softmax((x Wq^T + bq)(x Wk^T + bk)^T) (x Wv^T + bv)
// fp16 MFMA, fp32 accumulate. R7: R5 shape (4-wave blocks, 16 q-rows/wave,
// 8 waves/CU) + double-buffered global_load_lds prefetch (issue tile kt+1 right
// after the barrier, compute tile kt -> vmcnt drain at next barrier finds loads
// complete). Batch-major attn grid keeps each batch's K/V on one XCD's L2.
#define NN 1024
#define DD 256

typedef __attribute__((ext_vector_type(8))) _Float16 f16x8;  // 8 fp16 = 4 VGPRs
typedef __attribute__((ext_vector_type(4))) float f32x4;

union H8 { f16x8 v; _Float16 s[8]; };

__device__ __forceinline__ void g2lds16(const void* g, void* l) {
  __builtin_amdgcn_global_load_lds(
      (const __attribute__((address_space(1))) void*)g,
      (__attribute__((address_space(3))) void*)l, 16, 0, 0);
}

// ---------------- kernel 1: pack W fp32 -> fp16 fragment-major -----------------------
// pw chunk c = ((et*8+kk)*4+nt)*64+lane ; data = W[e=et*64+nt*16+col16][d=kk*32+quad*8..+7]
__global__ void wconv_kernel(const float* __restrict__ Wq, const float* __restrict__ Wk,
                             const float* __restrict__ Wv, _Float16* __restrict__ pw) {
  int c = blockIdx.x * 256 + threadIdx.x;        // < 24576
  int lane = c & 63;
  int nt = (c >> 6) & 3;
  int kk = (c >> 8) & 7;
  int et = c >> 11;                              // 0..11
  int e = et * 64 + nt * 16 + (lane & 15);
  int d = kk * 32 + (lane >> 4) * 8;
  const float* W = (e < 256) ? Wq : (e < 512 ? Wk : Wv);
  const float* src = W + (e & 255) * 256 + d;
  H8 xx;
  for (int j = 0; j < 8; ++j) xx.s[j] = (_Float16)src[j];
  *(f16x8*)(pw + (size_t)c * 8) = xx.v;
}

// ---------------- kernel 2: QKV projection -------------------------------------------
// grid 512 x 256 thr, 64 m-rows x all 768 e-cols. W tiles double-buffered via
// global_load_lds; q/k epilogues wave-private (no barrier), v keeps one barrier.
__global__ __launch_bounds__(256, 2) void proj_kernel(
    const float* __restrict__ traj,
    const float* __restrict__ bq, const float* __restrict__ bk, const float* __restrict__ bv,
    const _Float16* __restrict__ pw,
    _Float16* __restrict__ pq, _Float16* __restrict__ pk, _Float16* __restrict__ pv)
{
  __shared__ _Float16 Wl[2][16384];   // 2 x 32 KB W tiles, fragment-major
  __shared__ _Float16 Cs[64 * 88];    // 11264 B epilogue staging -> 76.8 KB total

  const int t = threadIdx.x;
  const int lane = t & 63, wave = t >> 6;
  const int col16 = lane & 15, quad = lane >> 4;
  const int mbase = blockIdx.x * 64;
  const int bb = mbase >> 10;

  // A fragments from global fp32 (A[m=lane&15][k=quad*8+j]); once per block.
  f16x8 aq[8];
  {
    const float* ap = traj + (size_t)(mbase + wave * 16 + col16) * DD;
    for (int kk = 0; kk < 8; ++kk) {
      float4 u0 = *(const float4*)(ap + kk * 32 + quad * 8);
      float4 u1 = *(const float4*)(ap + kk * 32 + quad * 8 + 4);
      H8 xx;
      xx.s[0] = (_Float16)u0.x; xx.s[1] = (_Float16)u0.y;
      xx.s[2] = (_Float16)u0.z; xx.s[3] = (_Float16)u0.w;
      xx.s[4] = (_Float16)u1.x; xx.s[5] = (_Float16)u1.y;
      xx.s[6] = (_Float16)u1.z; xx.s[7] = (_Float16)u1.w;
      aq[kk] = xx.v;
    }
  }

  const f32x4 zero = {0.f, 0.f, 0.f, 0.f};

  // prologue: stage tile 0 into buffer 0
  for (int i = 0; i < 8; ++i)
    g2lds16(pw + (size_t)(i * 256 + t) * 8, Wl[0] + (i * 256 + t) * 8);

  for (int et = 0; et < 12; ++et) {
    __syncthreads();                   // Wl[et&1] loads drained; prev Cs reads done
    if (et < 11) {                     // prefetch next W tile into other buffer
      const _Float16* ws = pw + (size_t)(et + 1) * 16384;
      _Float16* wd = Wl[(et + 1) & 1];
      for (int i = 0; i < 8; ++i)
        g2lds16(ws + (size_t)(i * 256 + t) * 8, wd + (i * 256 + t) * 8);
    }

    f32x4 acc[4];
    acc[0] = zero; acc[1] = zero; acc[2] = zero; acc[3] = zero;
    {
      const _Float16* wl = Wl[et & 1];
      for (int kk = 0; kk < 8; ++kk)
        for (int nt = 0; nt < 4; ++nt) {
          f16x8 bw = *(const f16x8*)&wl[((kk * 4 + nt) * 64 + lane) * 8];
          acc[nt] = __builtin_amdgcn_mfma_f32_16x16x32_f16(aq[kk], bw, acc[nt], 0, 0, 0);
        }
    }

    int ebase = et * 64;
    int sel = ebase >> 8;              // 0=q 1=k 2=v
    const float* bias = (sel == 0) ? bq : (sel == 1 ? bk : bv);
    for (int nt = 0; nt < 4; ++nt) {
      float bvl = bias[(ebase & 255) + nt * 16 + col16];
      acc[nt][0] += bvl; acc[nt][1] += bvl; acc[nt][2] += bvl; acc[nt][3] += bvl;
    }

    if (sel < 2) {
      // wave-private Cs round trip (rows wave*16..+15 only) -> no barrier
      for (int nt = 0; nt < 4; ++nt)
        for (int r = 0; r < 4; ++r)
          Cs[(wave * 16 + quad * 4 + r) * 88 + nt * 16 + col16] = (_Float16)acc[nt][r];
      if (sel == 0) {
        // pq[(g*8 + et*2 + kkloc)*64 + lane], A-frag layout, g = global 16-row group
        int g = (mbase >> 4) + wave;
        for (int kkloc = 0; kkloc < 2; ++kkloc) {
          f16x8 val = *(const f16x8*)&Cs[(wave * 16 + col16) * 88 + kkloc * 32 + quad * 8];
          *(f16x8*)(pq + (size_t)((g * 8 + et * 2 + kkloc) * 64 + lane) * 8) = val;
        }
      } else {
        // pk[((bb*64+kgg)*8+kkg)*64+lane]; wave handles key-group kg = wave
        int kgg = ((mbase & 1023) >> 4) + wave;
        for (int kk2 = 0; kk2 < 2; ++kk2) {
          f16x8 val = *(const f16x8*)&Cs[(wave * 16 + col16) * 88 + kk2 * 32 + quad * 8];
          int kkg = ((ebase - 256) >> 5) + kk2;
          *(f16x8*)(pk + (size_t)(((bb * 64 + kgg) * 8 + kkg) * 64 + lane) * 8) = val;
        }
      }
    } else {
      // v: transposed staging spans waves -> one barrier (prefetch mostly landed)
      for (int nt = 0; nt < 4; ++nt)
        for (int r = 0; r < 4; ++r)
          Cs[(nt * 16 + col16) * 88 + (wave * 16 + quad * 4 + r)] = (_Float16)acc[nt][r];
      __syncthreads();
      int kt64 = (mbase & 1023) >> 6;
      for (int i = 0; i < 2; ++i) {
        int cc = t + i * 256;
        int lane_c = cc & 63, k2 = (cc >> 6) & 1, dtl = cc >> 7;   // dtl 0..3
        f16x8 val = *(const f16x8*)&Cs[(dtl * 16 + (lane_c & 15)) * 88 +
                                       k2 * 32 + (lane_c >> 4) * 8];
        int dtg = ((ebase - 512) >> 4) + dtl;
        int kt32 = kt64 * 2 + k2;
        *(f16x8*)(pv + (size_t)(((bb * 32 + kt32) * 16 + dtg) * 64 + lane_c) * 8) = val;
      }
    }
  }
}

// ---------------- kernel 3: flash attention ------------------------------------------
// grid (32 batches, 16 q-tiles) x 256 thr; 4 waves, wave owns 16 q-rows. 32-key
// K/V tiles double-buffered via global_load_lds: prefetch kt+1 right after the
// barrier, compute kt. One barrier per kt. 70.7 KB LDS -> 2 blocks/CU, 8 waves/CU.
__global__ __launch_bounds__(256, 2) void attn_kernel(
    const _Float16* __restrict__ pq, const _Float16* __restrict__ pk,
    const _Float16* __restrict__ pv, float* __restrict__ out)
{
  __shared__ _Float16 Ks[2][8192];    // 2 x 16 KB: 32 keys x 256 d, fragment-major
  __shared__ _Float16 Vs[2][8192];    // 2 x 16 KB
  __shared__ _Float16 Ps[64 * 40];    // 5120 B, wave-private 16-row regions

  const int t = threadIdx.x;
  const int lane = t & 63, wave = t >> 6;
  const int col16 = lane & 15, quad = lane >> 4;
  const int b = blockIdx.x, qt = blockIdx.y;    // bid%8 = b%8 -> per-batch XCD
  const int qrow0 = b * NN + qt * 64;

  // Q fragments from packed global (lane-linear, once per kernel)
  f16x8 aq[8];
  {
    int g = b * 64 + qt * 4 + wave;
    for (int kk = 0; kk < 8; ++kk)
      aq[kk] = *(const f16x8*)(pq + (size_t)((g * 8 + kk) * 64 + lane) * 8);
  }

  float m_i[4], l_i[4], alpha[4];
  f32x4 O[16];
  const f32x4 zero = {0.f, 0.f, 0.f, 0.f};
  for (int r = 0; r < 4; ++r) { m_i[r] = -3.0e38f; l_i[r] = 0.f; }
  for (int dt = 0; dt < 16; ++dt) O[dt] = zero;

  const _Float16* kbb = pk + (size_t)b * 64 * 8 * 64 * 8;
  const _Float16* vbb = pv + (size_t)b * 32 * 16 * 64 * 8;

  // prologue: stage tile 0 into buffer 0
  for (int i = 0; i < 4; ++i)
    g2lds16(kbb + (size_t)(i * 256 + t) * 8, Ks[0] + (i * 256 + t) * 8);
  for (int i = 0; i < 4; ++i)
    g2lds16(vbb + (size_t)(i * 256 + t) * 8, Vs[0] + (i * 256 + t) * 8);

  for (int kt = 0; kt < 32; ++kt) {
    __syncthreads();                   // tile kt loads drained; prev reads of other buf done
    if (kt < 31) {                     // prefetch tile kt+1 into other buffer
      const _Float16* kg = kbb + (size_t)(kt + 1) * 8192;
      const _Float16* vg = vbb + (size_t)(kt + 1) * 8192;
      _Float16* kd = Ks[(kt + 1) & 1];
      _Float16* vd = Vs[(kt + 1) & 1];
      for (int i = 0; i < 4; ++i)
        g2lds16(kg + (size_t)(i * 256 + t) * 8, kd + (i * 256 + t) * 8);
      for (int i = 0; i < 4; ++i)
        g2lds16(vg + (size_t)(i * 256 + t) * 8, vd + (i * 256 + t) * 8);
    }
    const _Float16* ks = Ks[kt & 1];
    const _Float16* vs = Vs[kt & 1];

    // S = Q K^T (32 keys)
    f32x4 S[2]; S[0] = zero; S[1] = zero;
    for (int kk = 0; kk < 8; ++kk)
      for (int nt = 0; nt < 2; ++nt) {
        f16x8 bk_ = *(const f16x8*)&ks[((nt * 8 + kk) * 64 + lane) * 8];
        S[nt] = __builtin_amdgcn_mfma_f32_16x16x32_f16(aq[kk], bk_, S[nt], 0, 0, 0);
      }

    // online softmax — rows quad*4+r private to this wave's quads
    for (int r = 0; r < 4; ++r) {
      float vmax = fmaxf(S[0][r], S[1][r]);
      vmax = fmaxf(vmax, __shfl_xor(vmax, 1));
      vmax = fmaxf(vmax, __shfl_xor(vmax, 2));
      vmax = fmaxf(vmax, __shfl_xor(vmax, 4));
      vmax = fmaxf(vmax, __shfl_xor(vmax, 8));
      float nm = fmaxf(m_i[r], vmax);
      alpha[r] = __expf(m_i[r] - nm);
      float p0 = __expf(S[0][r] - nm);
      float p1 = __expf(S[1][r] - nm);
      S[0][r] = p0; S[1][r] = p1;
      float rs = p0 + p1;
      rs += __shfl_xor(rs, 1);
      rs += __shfl_xor(rs, 2);
      rs += __shfl_xor(rs, 4);
      rs += __shfl_xor(rs, 8);
      l_i[r] = l_i[r] * alpha[r] + rs;
      m_i[r] = nm;
    }
    for (int dt = 0; dt < 16; ++dt)
      for (int r = 0; r < 4; ++r) O[dt][r] *= alpha[r];

    // P -> LDS (C layout -> A layout; wave-private rows, no barrier)
    for (int nt = 0; nt < 2; ++nt)
      for (int r = 0; r < 4; ++r)
        Ps[(wave * 16 + quad * 4 + r) * 40 + nt * 16 + col16] = (_Float16)S[nt][r];
    f16x8 ap = *(const f16x8*)&Ps[(wave * 16 + col16) * 40 + quad * 8];

    // O += P V (one 32-k step per dt)
    for (int dt = 0; dt < 16; ++dt) {
      f16x8 bv_ = *(const f16x8*)&vs[(dt * 64 + lane) * 8];
      O[dt] = __builtin_amdgcn_mfma_f32_16x16x32_f16(ap, bv_, O[dt], 0, 0, 0);
    }
  }

  // epilogue: O /= l, fp32 store (lanes 0..15 contiguous 64B per instr)
  for (int r = 0; r < 4; ++r) {
    float inv = 1.0f / l_i[r];
    float* orow = out + (size_t)(qrow0 + wave * 16 + quad * 4 + r) * DD;
    for (int dt = 0; dt < 16; ++dt)
      orow[dt * 16 + col16] = O[dt][r] * inv;
  }
}

// ---------------- launch -------------------------------------------------------------
extern "C" void kernel_launch(void* const* d_in, const int* in_sizes, int n_in,
                              void* d_out, int out_size, void* d_ws, size_t ws_size,
                              hipStream_t stream) {
  const float* traj = (const float*)d_in[0];
  const float* Wq   = (const float*)d_in[1];
  const float* bq   = (const float*)d_in[2];
  const float* Wk   = (const float*)d_in[3];
  const float* bk   = (const float*)d_in[4];
  const float* Wv   = (const float*)d_in[5];
  const float* bv   = (const float*)d_in[6];

  // workspace (fp16): pq 16MB | pk 16MB | pv 16MB | pw 0.4MB  (all packed fragment-major)
  _Float16* pq = (_Float16*)d_ws;
  _Float16* pk = pq + (size_t)32768 * 256;
  _Float16* pv = pk + (size_t)32768 * 256;
  _Float16* pw = pv + (size_t)32768 * 256;   // ~48.4 MB total

  wconv_kernel<<<96, 256, 0, stream>>>(Wq, Wk, Wv, pw);
  proj_kernel<<<512, 256, 0, stream>>>(traj, bq, bk, bv, pw, pq, pk, pv);
  attn_kernel<<<dim3(32, 16), 256, 0, stream>>>(pq, pk, pv, (float*)d_out);
}

// Round 8
// 170.281 us; speedup vs baseline: 1.3135x; 1.0705x over previous
//
#include <hip/hip_runtime.h>

// B=32, N=1024, D=256. out = softmax((x Wq^T + bq)(x Wk^T + bk)^T) (x Wv^T + bv)
// fp16 MFMA, fp32 accumulate. R8: attn = 48KB LDS (K dbuf + single V + S-region
// reusing retired K buffer) -> 3 blocks/CU; A-layout softmax (scalar m/l/alpha,
// 4-8 shuffles, P packed to PV A-operand in regs); ballot-skipped O-rescale.
// proj = 128 rows/block (32/wave, 2 A-sets), e-split, wave-private epilogues.
#define NN 1024
#define DD 256

typedef __attribute__((ext_vector_type(8))) _Float16 f16x8;  // 8 fp16 = 4 VGPRs
typedef __attribute__((ext_vector_type(4))) float f32x4;

union H8 { f16x8 v; _Float16 s[8]; };

__device__ __forceinline__ void g2lds16(const void* g, void* l) {
  __builtin_amdgcn_global_load_lds(
      (const __attribute__((address_space(1))) void*)g,
      (__attribute__((address_space(3))) void*)l, 16, 0, 0);
}

// ---------------- kernel 1: pack W fp32 -> fp16 fragment-major (32-col tiles) -------
// chunk c = ((et*8+kk)*2+nt)*64+lane ; data = W[e=et*32+nt*16+c16][d=kk*32+qd*8..+7]
__global__ void wconv_kernel(const float* __restrict__ Wq, const float* __restrict__ Wk,
                             const float* __restrict__ Wv, _Float16* __restrict__ pw) {
  int c = blockIdx.x * 256 + threadIdx.x;        // < 24576
  int lane = c & 63;
  int nt = (c >> 6) & 1;
  int kk = (c >> 7) & 7;
  int et = c >> 10;                              // 0..23
  int e = et * 32 + nt * 16 + (lane & 15);
  int d = kk * 32 + (lane >> 4) * 8;
  const float* W = (e < 256) ? Wq : (e < 512 ? Wk : Wv);
  const float* src = W + (e & 255) * 256 + d;
  H8 xx;
  for (int j = 0; j < 8; ++j) xx.s[j] = (_Float16)src[j];
  *(f16x8*)(pw + (size_t)c * 8) = xx.v;
}

// ---------------- kernel 2: QKV projection -------------------------------------------
// grid 512 = 256 m-tiles x 2 e-halves; 4 waves, wave owns 32 m-rows (2 A-sets).
// 32-col W tiles dbuf'd via global_load_lds; all epilogues wave-private (no barriers).
__global__ __launch_bounds__(256, 2) void proj_kernel(
    const float* __restrict__ traj,
    const float* __restrict__ bq, const float* __restrict__ bk, const float* __restrict__ bv,
    const _Float16* __restrict__ pw,
    _Float16* __restrict__ pq, _Float16* __restrict__ pk, _Float16* __restrict__ pv)
{
  __shared__ alignas(16) _Float16 Wl[2][8192];   // 2 x 16 KB W tiles
  __shared__ alignas(16) _Float16 Cs[4][1280];   // per-wave 32x40 staging (2.5 KB each)

  const int t = threadIdx.x;
  const int lane = t & 63, wave = t >> 6;
  const int col16 = lane & 15, quad = lane >> 4;
  const int mt = blockIdx.x >> 1, eh = blockIdx.x & 1;
  const int mbase = mt * 128;
  const int bb = mbase >> 10;

  // A fragments, 2 sets of 16 rows (rows mbase + wave*32 + s*16 + col16)
  f16x8 aq[2][8];
  for (int s = 0; s < 2; ++s) {
    const float* ap = traj + (size_t)(mbase + wave * 32 + s * 16 + col16) * DD;
    for (int kk = 0; kk < 8; ++kk) {
      float4 u0 = *(const float4*)(ap + kk * 32 + quad * 8);
      float4 u1 = *(const float4*)(ap + kk * 32 + quad * 8 + 4);
      H8 xx;
      xx.s[0] = (_Float16)u0.x; xx.s[1] = (_Float16)u0.y;
      xx.s[2] = (_Float16)u0.z; xx.s[3] = (_Float16)u0.w;
      xx.s[4] = (_Float16)u1.x; xx.s[5] = (_Float16)u1.y;
      xx.s[6] = (_Float16)u1.z; xx.s[7] = (_Float16)u1.w;
      aq[s][kk] = xx.v;
    }
  }

  const f32x4 zero = {0.f, 0.f, 0.f, 0.f};
  const int et0 = eh * 12;

  // prologue: stage first W tile
  for (int i = 0; i < 4; ++i)
    g2lds16(pw + (size_t)et0 * 8192 + (size_t)(i * 256 + t) * 8, Wl[0] + (i * 256 + t) * 8);

  for (int ei = 0; ei < 12; ++ei) {
    __syncthreads();                   // tile ei landed; prev tile's reads done
    if (ei < 11) {
      const _Float16* ws = pw + (size_t)(et0 + ei + 1) * 8192;
      _Float16* wd = Wl[(ei + 1) & 1];
      for (int i = 0; i < 4; ++i)
        g2lds16(ws + (size_t)(i * 256 + t) * 8, wd + (i * 256 + t) * 8);
    }
    const _Float16* wl = Wl[ei & 1];

    f32x4 acc[2][2];
    acc[0][0] = zero; acc[0][1] = zero; acc[1][0] = zero; acc[1][1] = zero;
    for (int kk = 0; kk < 8; ++kk)
      for (int nt = 0; nt < 2; ++nt) {
        f16x8 bw = *(const f16x8*)&wl[((kk * 2 + nt) * 64 + lane) * 8];
        acc[0][nt] = __builtin_amdgcn_mfma_f32_16x16x32_f16(aq[0][kk], bw, acc[0][nt], 0, 0, 0);
        acc[1][nt] = __builtin_amdgcn_mfma_f32_16x16x32_f16(aq[1][kk], bw, acc[1][nt], 0, 0, 0);
      }

    int e0 = eh * 384 + ei * 32;
    int sel = e0 >> 8;                 // 0=q 1=k 2=v
    const float* bias = (sel == 0) ? bq : (sel == 1 ? bk : bv);
    for (int nt = 0; nt < 2; ++nt) {
      float bvl = bias[(e0 & 255) + nt * 16 + col16];
      for (int s = 0; s < 2; ++s) {
        acc[s][nt][0] += bvl; acc[s][nt][1] += bvl;
        acc[s][nt][2] += bvl; acc[s][nt][3] += bvl;
      }
    }

    _Float16* cs = Cs[wave];           // wave-private: in-order DS pipe, no barriers
    if (sel < 2) {
      // C-layout staging: row = s*16+quad*4+r (stride 40), col = nt*16+col16
      for (int s = 0; s < 2; ++s)
        for (int nt = 0; nt < 2; ++nt)
          for (int r = 0; r < 4; ++r)
            cs[(s * 16 + quad * 4 + r) * 40 + nt * 16 + col16] = (_Float16)acc[s][nt][r];
      if (sel == 0) {
        for (int s = 0; s < 2; ++s) {
          f16x8 val = *(const f16x8*)&cs[(s * 16 + col16) * 40 + quad * 8];
          int g = (mbase >> 4) + wave * 2 + s;
          *(f16x8*)(pq + (size_t)((g * 8 + ei) * 64 + lane) * 8) = val;   // kk = ei (eh=0)
        }
      } else {
        int kkg = (e0 - 256) >> 5;
        for (int s = 0; s < 2; ++s) {
          f16x8 val = *(const f16x8*)&cs[(s * 16 + col16) * 40 + quad * 8];
          int kgg = ((mbase & 1023) >> 4) + wave * 2 + s;
          *(f16x8*)(pk + (size_t)(((bb * 64 + kgg) * 8 + kkg) * 64 + lane) * 8) = val;
        }
      }
    } else {
      // transposed staging: row = e_local = nt*16+col16 (stride 40), col = m 0..31
      for (int s = 0; s < 2; ++s)
        for (int nt = 0; nt < 2; ++nt)
          for (int r = 0; r < 4; ++r)
            cs[(nt * 16 + col16) * 40 + s * 16 + quad * 4 + r] = (_Float16)acc[s][nt][r];
      int kt32 = ((mbase & 1023) >> 5) + wave;   // wave's 32 rows = one 32-key group
      for (int dtl = 0; dtl < 2; ++dtl) {
        f16x8 val = *(const f16x8*)&cs[(dtl * 16 + col16) * 40 + quad * 8];
        int dtg = ((e0 - 512) >> 4) + dtl;
        *(f16x8*)(pv + (size_t)(((bb * 32 + kt32) * 16 + dtg) * 64 + lane) * 8) = val;
      }
    }
  }
}

// ---------------- kernel 3: flash attention ------------------------------------------
// grid (32 b, 16 qt) x 256 thr; 4 waves x 16 q-rows. K dbuf + single V + S-region
// reusing retired K buffer -> 48 KB LDS, 3 blocks/CU. A-layout softmax.
__global__ __launch_bounds__(256, 3) void attn_kernel(
    const _Float16* __restrict__ pq, const _Float16* __restrict__ pk,
    const _Float16* __restrict__ pv, float* __restrict__ out)
{
  __shared__ alignas(16) _Float16 Ks[2][8192];   // 2 x 16 KB (32 keys x 256 d)
  __shared__ alignas(16) _Float16 Vs[8192];      // 16 KB

  const int t = threadIdx.x;
  const int lane = t & 63, wave = t >> 6;
  const int col16 = lane & 15, quad = lane >> 4;
  const int b = blockIdx.x, qt = blockIdx.y;     // bid%8 = b%8 -> per-batch XCD
  const int qrow0 = b * NN + qt * 64;

  // Q fragments from packed global
  f16x8 aq[8];
  {
    int g = b * 64 + qt * 4 + wave;
    for (int kk = 0; kk < 8; ++kk)
      aq[kk] = *(const f16x8*)(pq + (size_t)((g * 8 + kk) * 64 + lane) * 8);
  }

  float m_i = -3.0e38f, l_i = 0.f;    // A-layout scalars: this lane's row = col16
  f32x4 O[16];
  const f32x4 zero = {0.f, 0.f, 0.f, 0.f};
  for (int dt = 0; dt < 16; ++dt) O[dt] = zero;

  const _Float16* kbb = pk + (size_t)b * 64 * 8 * 64 * 8;
  const _Float16* vbb = pv + (size_t)b * 32 * 16 * 64 * 8;

  // prologue: stage K tile 0
  for (int i = 0; i < 4; ++i)
    g2lds16(kbb + (size_t)(i * 256 + t) * 8, Ks[0] + (i * 256 + t) * 8);

  for (int kt = 0; kt < 32; ++kt) {
    __syncthreads();                   // A: K[kt] landed; all PV reads of Vs done
    {                                  // issue V[kt] (single buffer) + K[kt+1] prefetch
      const _Float16* vg = vbb + (size_t)kt * 8192;
      for (int i = 0; i < 4; ++i)
        g2lds16(vg + (size_t)(i * 256 + t) * 8, Vs + (i * 256 + t) * 8);
      if (kt < 31) {
        const _Float16* kg = kbb + (size_t)(kt + 1) * 8192;
        _Float16* kd = Ks[(kt + 1) & 1];
        for (int i = 0; i < 4; ++i)
          g2lds16(kg + (size_t)(i * 256 + t) * 8, kd + (i * 256 + t) * 8);
      }
    }

    // S = Q K^T (32 keys) from current K buffer
    const _Float16* ks = Ks[kt & 1];
    f32x4 S[2]; S[0] = zero; S[1] = zero;
    for (int kk = 0; kk < 8; ++kk)
      for (int nt = 0; nt < 2; ++nt) {
        f16x8 bk_ = *(const f16x8*)&ks[((nt * 8 + kk) * 64 + lane) * 8];
        S[nt] = __builtin_amdgcn_mfma_f32_16x16x32_f16(aq[kk], bk_, S[nt], 0, 0, 0);
      }

    __syncthreads();                   // B: K reads done (S-region safe); V[kt] landed

    // S fp32 -> retired K buffer (C layout), read back A-layout (8 keys/lane)
    float* Sp = (float*)Ks[kt & 1];    // 64 rows x stride 36 words = 9216 B
    for (int nt = 0; nt < 2; ++nt)
      for (int r = 0; r < 4; ++r)
        Sp[(wave * 16 + quad * 4 + r) * 36 + nt * 16 + col16] = S[nt][r];
    float sv[8];
    *(f32x4*)&sv[0] = *(const f32x4*)&Sp[(wave * 16 + col16) * 36 + quad * 8];
    *(f32x4*)&sv[4] = *(const f32x4*)&Sp[(wave * 16 + col16) * 36 + quad * 8 + 4];

    // softmax in A-layout: row = col16, keys quad*8..+7
    float vmax = sv[0];
    for (int j = 1; j < 8; ++j) vmax = fmaxf(vmax, sv[j]);
    vmax = fmaxf(vmax, __shfl_xor(vmax, 16));
    vmax = fmaxf(vmax, __shfl_xor(vmax, 32));
    float nm = fmaxf(m_i, vmax);
    float alpha = __expf(m_i - nm);
    float rs = 0.f;
    H8 px;
    for (int j = 0; j < 8; ++j) {
      float pj = __expf(sv[j] - nm);
      rs += pj;
      px.s[j] = (_Float16)pj;
    }
    rs += __shfl_xor(rs, 16);
    rs += __shfl_xor(rs, 32);
    l_i = l_i * alpha + rs;
    m_i = nm;
    f16x8 ap = px.v;                   // PV A-operand straight from registers

    // O-rescale only when some row's max moved (exact skip: alpha==1 otherwise)
    if (__ballot(alpha < 1.0f)) {
      float a4[4];
      for (int r = 0; r < 4; ++r) a4[r] = __shfl(alpha, quad * 4 + r);
      for (int dt = 0; dt < 16; ++dt)
        for (int r = 0; r < 4; ++r) O[dt][r] *= a4[r];
    }

    // O += P V
    for (int dt = 0; dt < 16; ++dt) {
      f16x8 bv_ = *(const f16x8*)&Vs[(dt * 64 + lane) * 8];
      O[dt] = __builtin_amdgcn_mfma_f32_16x16x32_f16(ap, bv_, O[dt], 0, 0, 0);
    }
  }

  // epilogue: O /= l (broadcast l to C-layout), fp32 store
  float linv[4];
  for (int r = 0; r < 4; ++r) linv[r] = 1.0f / __shfl(l_i, quad * 4 + r);
  for (int r = 0; r < 4; ++r) {
    float* orow = out + (size_t)(qrow0 + wave * 16 + quad * 4 + r) * DD;
    for (int dt = 0; dt < 16; ++dt)
      orow[dt * 16 + col16] = O[dt][r] * linv[r];
  }
}

// ---------------- launch -------------------------------------------------------------
extern "C" void kernel_launch(void* const* d_in, const int* in_sizes, int n_in,
                              void* d_out, int out_size, void* d_ws, size_t ws_size,
                              hipStream_t stream) {
  const float* traj = (const float*)d_in[0];
  const float* Wq   = (const float*)d_in[1];
  const float* bq   = (const float*)d_in[2];
  const float* Wk   = (const float*)d_in[3];
  const float* bk   = (const float*)d_in[4];
  const float* Wv   = (const float*)d_in[5];
  const float* bv   = (const float*)d_in[6];

  // workspace (fp16): pq 16MB | pk 16MB | pv 16MB | pw 0.4MB  (all packed fragment-major)
  _Float16* pq = (_Float16*)d_ws;
  _Float16* pk = pq + (size_t)32768 * 256;
  _Float16* pv = pk + (size_t)32768 * 256;
  _Float16* pw = pv + (size_t)32768 * 256;   // ~48.4 MB total

  wconv_kernel<<<96, 256, 0, stream>>>(Wq, Wk, Wv, pw);
  proj_kernel<<<512, 256, 0, stream>>>(traj, bq, bk, bv, pw, pq, pk, pv);
  attn_kernel<<<dim3(32, 16), 256, 0, stream>>>(pq, pk, pv, (float*)d_out);
}